// Round 4
// baseline (450.119 us; speedup 1.0000x reference)
//
#include <hip/hip_runtime.h>

typedef __attribute__((ext_vector_type(8))) short short8;
typedef __attribute__((ext_vector_type(4))) float floatx4;

#define LDK 136                    // padded LDS row (bf16 units): 272 B
#define LDS_BYTES (256 * LDK * 2)  // 69632 B: full V^T (256 d-rows x 128 k)

__device__ __forceinline__ unsigned f2bf1(float x) {
    unsigned u = __builtin_bit_cast(unsigned, x);
    return (u + 0x7fffu + ((u >> 16) & 1u)) >> 16;
}
__device__ __forceinline__ unsigned packbf(float lo, float hi) {
    return f2bf1(lo) | (f2bf1(hi) << 16);
}

// Inline-asm global load: position-pinned (IR passes cannot sink it the way
// they sink C++ loads across sched_barrier). Result is NOT valid until an
// explicit s_waitcnt vmcnt(0).
#define VL(reg, p, o) \
    asm volatile("global_load_dwordx4 %0, %1, off offset:" o \
                 : "=v"(reg) : "v"(p) : "memory")

// Pass1 (ACCUM=false): tile=(b,r), s0=128*256, s1=256.
// Pass2 (ACCUM=true):  tile=(b,c), s0=256, s1=128*256.
// grid 512, 2 tiles/block (ti, ti+512), 2 blocks/CU. Per tile:
//   softmax(A)->bfrag (in-register) | V asm-loads in flight
//   vmcnt(0) -> stage V^T -> lgkmcnt(0) -> issue NEXT tile's V (asm)
//   -> s_barrier -> MFMA (pass2: out folded into acc-init) -> s_barrier
// Tile-1's V loads stay outstanding across barrier+MFMA0+epilogue0: the wave
// always has ~256B/lane in flight instead of bursting then idling.
template <bool ACCUM>
__global__ __launch_bounds__(512, 4) void gtrans(
    const float* __restrict__ atten, const float* __restrict__ value,
    float* __restrict__ out, const float* __restrict__ shiftp,
    const float* __restrict__ biasp, int s0, int s1)
{
    extern __shared__ short Buf[];
    unsigned* Buf32 = (unsigned*)Buf;

    const int tid  = threadIdx.x;
    const int lane = tid & 63;
    const int w    = tid >> 6;

    const float shift = shiftp[0];
    const float bias  = biasp[0];

    const int rrow = 16 * w + (lane & 15);     // this lane's c-row
    const int kq8  = (lane >> 4) * 8;          // k-subchunk base (MFMA B layout)
    const int k0   = 16 * w + 2 * (lane >> 3); // V staging: even k-row
    const int d0   = 4 * (lane & 7);           // V staging: d-quad base
    const int am   = lane & 15;
    const int dq   = 4 * (lane >> 4);

    floatx4 va[8], vb[8];   // V in flight / staged (reused across tiles)
    short8 bfrag[4];

    auto issueV = [&](int ti) {
        const int b = ti >> 7, i = ti & 127;
        const float* vp0 = value + (size_t)b * (128 * 128 * 256) + (size_t)i * s0
                         + (size_t)k0 * s1 + d0;
        const float* vp1 = vp0 + s1;
        VL(va[0], vp0, "0");   VL(va[1], vp0, "128"); VL(va[2], vp0, "256");
        VL(va[3], vp0, "384"); VL(va[4], vp0, "512"); VL(va[5], vp0, "640");
        VL(va[6], vp0, "768"); VL(va[7], vp0, "896");
        VL(vb[0], vp1, "0");   VL(vb[1], vp1, "128"); VL(vb[2], vp1, "256");
        VL(vb[3], vp1, "384"); VL(vb[4], vp1, "512"); VL(vb[5], vp1, "640");
        VL(vb[6], vp1, "768"); VL(vb[7], vp1, "896");
    };

    auto softmax_bfrag = [&](int ti) {
        const float* abase = atten + (size_t)ti * (128 * 128);
        floatx4 aA[8];
#pragma unroll
        for (int ks = 0; ks < 4; ++ks) {
            const float* ap = abase + rrow * 128 + ks * 32 + kq8;
            aA[2 * ks]     = *(const floatx4*)(ap);
            aA[2 * ks + 1] = *(const floatx4*)(ap + 4);
        }
        floatx4 e8[8];
        float mx = -1e30f;
#pragma unroll
        for (int j = 0; j < 8; ++j) {
            const int kb = (j >> 1) * 32 + kq8 + (j & 1) * 4;
            floatx4 v = aA[j], t;
#pragma unroll
            for (int e = 0; e < 4; ++e) {
                float d = (float)(kb + e - rrow);
                t[e] = v[e] - (shift * d * d + bias);
            }
            e8[j] = t;
            mx = fmaxf(mx, fmaxf(fmaxf(t[0], t[1]), fmaxf(t[2], t[3])));
        }
        mx = fmaxf(mx, __shfl_xor(mx, 16, 64));
        mx = fmaxf(mx, __shfl_xor(mx, 32, 64));
        float ssum = 0.0f;
#pragma unroll
        for (int j = 0; j < 8; ++j) {
            floatx4 t = e8[j];
#pragma unroll
            for (int e = 0; e < 4; ++e) t[e] = __expf(t[e] - mx);
            e8[j] = t;
            ssum += (t[0] + t[1]) + (t[2] + t[3]);
        }
        ssum += __shfl_xor(ssum, 16, 64);
        ssum += __shfl_xor(ssum, 32, 64);
        float r = 1.0f / ssum;
#pragma unroll
        for (int ks = 0; ks < 4; ++ks) {
            union { short8 s; unsigned u[4]; } uu;
            floatx4 lo = e8[2 * ks], hi = e8[2 * ks + 1];
            uu.u[0] = packbf(lo[0] * r, lo[1] * r);
            uu.u[1] = packbf(lo[2] * r, lo[3] * r);
            uu.u[2] = packbf(hi[0] * r, hi[1] * r);
            uu.u[3] = packbf(hi[2] * r, hi[3] * r);
            bfrag[ks] = uu.s;
        }
    };

    auto stage = [&]() {
#pragma unroll
        for (int q = 0; q < 8; ++q)
#pragma unroll
            for (int e = 0; e < 4; ++e)
                Buf32[(d0 + 32 * q + e) * (LDK / 2) + (k0 >> 1)] = packbf(va[q][e], vb[q][e]);
    };

    auto mfma_phase = [&](int ti) {
        const int b = ti >> 7, i = ti & 127;
        float* orow = out + (size_t)b * (128 * 128 * 256) + (size_t)i * s0
                    + (size_t)rrow * s1 + dq;
#pragma unroll
        for (int g = 0; g < 4; ++g) {
            floatx4 acc[4];
            if (ACCUM) {
#pragma unroll
                for (int t = 0; t < 4; ++t)
                    acc[t] = *(const floatx4*)(orow + g * 64 + t * 16);   // C-in = old out
            } else {
#pragma unroll
                for (int t = 0; t < 4; ++t) acc[t] = (floatx4)0.0f;
            }
#pragma unroll
            for (int tt = 0; tt < 4; ++tt) {
                const short* base = &Buf[((g * 4 + tt) * 16 + am) * LDK + kq8];
#pragma unroll
                for (int ks = 0; ks < 4; ++ks) {
                    short8 af = *(const short8*)(base + ks * 32);
                    acc[tt] = __builtin_amdgcn_mfma_f32_16x16x32_bf16(af, bfrag[ks], acc[tt], 0, 0, 0);
                }
            }
#pragma unroll
            for (int t = 0; t < 4; ++t)
                *(floatx4*)(orow + g * 64 + t * 16) = acc[t];
        }
    };

    const int ti0 = blockIdx.x;
    const int ti1 = blockIdx.x + 512;

    // ================= tile 0 =================
    issueV(ti0);                       // asm loads: pinned issue, fly under softmax
    softmax_bfrag(ti0);                // backend drains A (and V0 with it; both needed soon)
    __builtin_amdgcn_sched_barrier(0);
    asm volatile("s_waitcnt vmcnt(0)" ::: "memory");   // V0 results valid
    __builtin_amdgcn_sched_barrier(0);
    stage();
    __builtin_amdgcn_sched_barrier(0);
    asm volatile("s_waitcnt lgkmcnt(0)" ::: "memory"); // ds_writes done -> va/vb free
    issueV(ti1);                       // tile-1 V in flight across barrier + MFMA0
    __builtin_amdgcn_s_barrier();
    mfma_phase(ti0);
    __builtin_amdgcn_s_barrier();      // all waves done reading LDS before restage

    // ================= tile 1 =================
    softmax_bfrag(ti1);
    __builtin_amdgcn_sched_barrier(0);
    asm volatile("s_waitcnt vmcnt(0)" ::: "memory");   // V1 results valid
    __builtin_amdgcn_sched_barrier(0);
    stage();
    __builtin_amdgcn_sched_barrier(0);
    asm volatile("s_waitcnt lgkmcnt(0)" ::: "memory");
    __builtin_amdgcn_s_barrier();
    mfma_phase(ti1);
}

extern "C" void kernel_launch(void* const* d_in, const int* in_sizes, int n_in,
                              void* d_out, int out_size, void* d_ws, size_t ws_size,
                              hipStream_t stream) {
    const float* atten_x = (const float*)d_in[1];
    const float* atten_y = (const float*)d_in[2];
    const float* value   = (const float*)d_in[3];
    const float* shiftp  = (const float*)d_in[4];
    const float* biasp   = (const float*)d_in[5];
    float* out = (float*)d_out;

    static bool inited = false;
    if (!inited) {
        hipFuncSetAttribute((const void*)&gtrans<false>,
                            hipFuncAttributeMaxDynamicSharedMemorySize, LDS_BYTES);
        hipFuncSetAttribute((const void*)&gtrans<true>,
                            hipFuncAttributeMaxDynamicSharedMemorySize, LDS_BYTES);
        inited = true;
    }

    dim3 grid(512), block(512);
    // Pass 1: out = einsum('brck,brkd->brcd', softmax(Ax+gx), value)
    gtrans<false><<<grid, block, LDS_BYTES, stream>>>(atten_x, value, out, shiftp, biasp,
                                                      128 * 256, 256);
    // Pass 2: out += einsum('bcrk,bkcd->brcd', softmax(Ay+gy), value)
    gtrans<true><<<grid, block, LDS_BYTES, stream>>>(atten_y, value, out, shiftp, biasp,
                                                     256, 128 * 256);
}

// Round 5
// 365.377 us; speedup vs baseline: 1.2319x; 1.2319x over previous
//
#include <hip/hip_runtime.h>

typedef __attribute__((ext_vector_type(8))) short short8;
typedef __attribute__((ext_vector_type(4))) float floatx4;
typedef _Float16 half4 __attribute__((ext_vector_type(4)));

#define LDK 136                    // padded LDS row (bf16 units): 272 B
#define LDS_BYTES (256 * LDK * 2)  // 69632 B: full V^T (256 d-rows x 128 k)
#define OUT_ELEMS (8LL * 128 * 128 * 256)

__device__ __forceinline__ unsigned f2bf1(float x) {
    unsigned u = __builtin_bit_cast(unsigned, x);
    return (u + 0x7fffu + ((u >> 16) & 1u)) >> 16;
}
__device__ __forceinline__ unsigned packbf(float lo, float hi) {
    return f2bf1(lo) | (f2bf1(hi) << 16);
}

// MODE 0: pass1 -> out fp32              (fallback, no ws)
// MODE 1: pass1 -> ws fp16               (saves 67 MB write; ws stays in L3)
// MODE 2: pass2, out += (read fp32 out)  (fallback)
// MODE 3: pass2, out = ws(fp16) + P*V, nontemporal final store
// Structure = R2's single-barrier kernel (best measured):
//   A loads (nontemporal) -> V loads -> softmax+bfrag in-register
//   -> stage full V^T in LDS -> lgkmcnt(0) + s_barrier -> 4 MFMA groups + epilogue.
template <int MODE>
__global__ __launch_bounds__(512, 4) void gtrans(
    const float* __restrict__ atten, const float* __restrict__ value,
    float* __restrict__ out, _Float16* __restrict__ ws,
    const float* __restrict__ shiftp, const float* __restrict__ biasp,
    int s0, int s1)
{
    extern __shared__ short Buf[];
    unsigned* Buf32 = (unsigned*)Buf;

    const int bi   = blockIdx.x;
    const int b    = bi >> 7;
    const int i    = bi & 127;
    const int tid  = threadIdx.x;
    const int lane = tid & 63;
    const int w    = tid >> 6;

    const float shift = shiftp[0];
    const float bias  = biasp[0];

    const size_t obase_off = (size_t)b * (128 * 128 * 256) + (size_t)i * s0;
    const float* abase = atten + (size_t)bi * (128 * 128);
    const float* vbase = value + obase_off;

    const int rrow = 16 * w + (lane & 15);     // this lane's c-row (pass1) / r-row (pass2)
    const int kq8  = (lane >> 4) * 8;          // k-subchunk base (MFMA fragment layout)
    const int k0   = 16 * w + 2 * (lane >> 3); // V staging: even k-row
    const int d0   = 4 * (lane & 7);           // V staging: d-quad base
    const int am   = lane & 15;
    const int dq   = 4 * (lane >> 4);

    // ---- A loads: nontemporal (stream-once; keep L3 for value/ws)
    floatx4 aA[8];
#pragma unroll
    for (int ks = 0; ks < 4; ++ks) {
        const float* ap = abase + rrow * 128 + ks * 32 + kq8;
        aA[2 * ks]     = __builtin_nontemporal_load((const floatx4*)(ap));
        aA[2 * ks + 1] = __builtin_nontemporal_load((const floatx4*)(ap + 4));
    }
    // ---- V loads (cacheable: re-read by pass2 from L3)
    floatx4 va[8], vb[8];
    {
        const float* vp0 = vbase + (size_t)k0 * s1 + d0;
        const float* vp1 = vp0 + s1;
#pragma unroll
        for (int q = 0; q < 8; ++q) va[q] = *(const floatx4*)(vp0 + 32 * q);
#pragma unroll
        for (int q = 0; q < 8; ++q) vb[q] = *(const floatx4*)(vp1 + 32 * q);
    }

    // ---- Softmax, row-per-lane; 4 lanes (l, l^16, l^32, l^48) share a row
    short8 bfrag[4];
    {
        floatx4 e8[8];
        float mx = -1e30f;
#pragma unroll
        for (int j = 0; j < 8; ++j) {
            const int kb = (j >> 1) * 32 + kq8 + (j & 1) * 4;
            floatx4 v = aA[j], t;
#pragma unroll
            for (int e = 0; e < 4; ++e) {
                float d = (float)(kb + e - rrow);
                t[e] = v[e] - (shift * d * d + bias);
            }
            e8[j] = t;
            mx = fmaxf(mx, fmaxf(fmaxf(t[0], t[1]), fmaxf(t[2], t[3])));
        }
        mx = fmaxf(mx, __shfl_xor(mx, 16, 64));
        mx = fmaxf(mx, __shfl_xor(mx, 32, 64));
        float ssum = 0.0f;
#pragma unroll
        for (int j = 0; j < 8; ++j) {
            floatx4 t = e8[j];
#pragma unroll
            for (int e = 0; e < 4; ++e) t[e] = __expf(t[e] - mx);
            e8[j] = t;
            ssum += (t[0] + t[1]) + (t[2] + t[3]);
        }
        ssum += __shfl_xor(ssum, 16, 64);
        ssum += __shfl_xor(ssum, 32, 64);
        float r = 1.0f / ssum;
#pragma unroll
        for (int ks = 0; ks < 4; ++ks) {
            union { short8 s; unsigned u[4]; } uu;
            floatx4 lo = e8[2 * ks], hi = e8[2 * ks + 1];
            uu.u[0] = packbf(lo[0] * r, lo[1] * r);
            uu.u[1] = packbf(lo[2] * r, lo[3] * r);
            uu.u[2] = packbf(hi[0] * r, hi[1] * r);
            uu.u[3] = packbf(hi[2] * r, hi[3] * r);
            bfrag[ks] = uu.s;
        }
    }

    // ---- Stage full V^T (packed k-pair u32 writes)
#pragma unroll
    for (int q = 0; q < 8; ++q)
#pragma unroll
        for (int e = 0; e < 4; ++e)
            Buf32[(d0 + 32 * q + e) * (LDK / 2) + (k0 >> 1)] = packbf(va[q][e], vb[q][e]);

    // ---- ONE barrier: drain LDS writes only
    __builtin_amdgcn_sched_barrier(0);
    asm volatile("s_waitcnt lgkmcnt(0)" ::: "memory");
    __builtin_amdgcn_s_barrier();

    // ---- 4 groups of 4 d-tiles: MFMA + epilogue
    float*     orow = out + obase_off + (size_t)rrow * s1 + dq;
    _Float16*  wrow = ws  + obase_off + (size_t)rrow * s1 + dq;
#pragma unroll
    for (int g = 0; g < 4; ++g) {
        floatx4 acc[4];
        if (MODE == 2) {
#pragma unroll
            for (int t = 0; t < 4; ++t)
                acc[t] = *(const floatx4*)(orow + g * 64 + t * 16);
        } else if (MODE == 3) {
#pragma unroll
            for (int t = 0; t < 4; ++t) {
                half4 h = *(const half4*)(wrow + g * 64 + t * 16);
                floatx4 f;
#pragma unroll
                for (int e = 0; e < 4; ++e) f[e] = (float)h[e];
                acc[t] = f;
            }
        } else {
#pragma unroll
            for (int t = 0; t < 4; ++t) acc[t] = (floatx4)0.0f;
        }
#pragma unroll
        for (int tt = 0; tt < 4; ++tt) {
            const short* base = &Buf[((g * 4 + tt) * 16 + am) * LDK + kq8];
#pragma unroll
            for (int ks = 0; ks < 4; ++ks) {
                short8 af = *(const short8*)(base + ks * 32);
                acc[tt] = __builtin_amdgcn_mfma_f32_16x16x32_bf16(af, bfrag[ks], acc[tt], 0, 0, 0);
            }
        }
#pragma unroll
        for (int t = 0; t < 4; ++t) {
            if (MODE == 1) {
                half4 h;
#pragma unroll
                for (int e = 0; e < 4; ++e) h[e] = (_Float16)acc[t][e];
                *(half4*)(wrow + g * 64 + t * 16) = h;
            } else if (MODE == 3) {
                __builtin_nontemporal_store(acc[t], (floatx4*)(orow + g * 64 + t * 16));
            } else {
                *(floatx4*)(orow + g * 64 + t * 16) = acc[t];
            }
        }
    }
}

extern "C" void kernel_launch(void* const* d_in, const int* in_sizes, int n_in,
                              void* d_out, int out_size, void* d_ws, size_t ws_size,
                              hipStream_t stream) {
    const float* atten_x = (const float*)d_in[1];
    const float* atten_y = (const float*)d_in[2];
    const float* value   = (const float*)d_in[3];
    const float* shiftp  = (const float*)d_in[4];
    const float* biasp   = (const float*)d_in[5];
    float* out = (float*)d_out;
    _Float16* ws = (_Float16*)d_ws;

    static bool inited = false;
    if (!inited) {
        hipFuncSetAttribute((const void*)&gtrans<0>, hipFuncAttributeMaxDynamicSharedMemorySize, LDS_BYTES);
        hipFuncSetAttribute((const void*)&gtrans<1>, hipFuncAttributeMaxDynamicSharedMemorySize, LDS_BYTES);
        hipFuncSetAttribute((const void*)&gtrans<2>, hipFuncAttributeMaxDynamicSharedMemorySize, LDS_BYTES);
        hipFuncSetAttribute((const void*)&gtrans<3>, hipFuncAttributeMaxDynamicSharedMemorySize, LDS_BYTES);
        inited = true;
    }

    const bool use_ws = (ws != nullptr) && (ws_size >= (size_t)OUT_ELEMS * sizeof(_Float16));

    dim3 grid(1024), block(512);
    if (use_ws) {
        // Pass 1: ws(fp16) = einsum('brck,brkd->brcd', softmax(Ax+gx), value)
        gtrans<1><<<grid, block, LDS_BYTES, stream>>>(atten_x, value, out, ws, shiftp, biasp,
                                                      128 * 256, 256);
        // Pass 2: out = ws + einsum('bcrk,bkcd->brcd', softmax(Ay+gy), value)
        gtrans<3><<<grid, block, LDS_BYTES, stream>>>(atten_y, value, out, ws, shiftp, biasp,
                                                      256, 128 * 256);
    } else {
        gtrans<0><<<grid, block, LDS_BYTES, stream>>>(atten_x, value, out, ws, shiftp, biasp,
                                                      128 * 256, 256);
        gtrans<2><<<grid, block, LDS_BYTES, stream>>>(atten_y, value, out, ws, shiftp, biasp,
                                                      256, 128 * 256);
    }
}

// Round 6
// 363.914 us; speedup vs baseline: 1.2369x; 1.0040x over previous
//
#include <hip/hip_runtime.h>

typedef __attribute__((ext_vector_type(8))) short short8;
typedef __attribute__((ext_vector_type(4))) float floatx4;
typedef _Float16 half4 __attribute__((ext_vector_type(4)));

#define LDK 136                    // padded LDS row (bf16): 272 B, 16B-aligned
#define LDS_BYTES (128 * LDK * 2)  // 34816 B: V^T d-half (128 d-rows x 128 k) -> 4 blocks/CU
#define OUT_ELEMS (8LL * 128 * 128 * 256)

__device__ __forceinline__ unsigned f2bf1(float x) {
    unsigned u = __builtin_bit_cast(unsigned, x);
    return (u + 0x7fffu + ((u >> 16) & 1u)) >> 16;
}
__device__ __forceinline__ unsigned packbf(float lo, float hi) {
    return f2bf1(lo) | (f2bf1(hi) << 16);
}

// MODE 0: pass1 -> out fp32 (fallback, no ws)
// MODE 1: pass1 -> ws fp16
// MODE 2: pass2, out += (read fp32 out)  (fallback)
// MODE 3: pass2, out = ws(fp16) + P*V, nontemporal final store
//
// R6: occupancy-first. LDS halved to 34816 B (V^T staged in two d-halves,
// k complete within each half so acc retires per-group) and
// __launch_bounds__(512,8) forces <=64 VGPR -> 4 blocks/CU, 32 waves/CU,
// all 1024 blocks resident in ONE round. Latency hiding via TLP, not ILP.
template <int MODE>
__global__ __launch_bounds__(512, 8) void gtrans(
    const float* __restrict__ atten, const float* __restrict__ value,
    float* __restrict__ out, _Float16* __restrict__ ws,
    const float* __restrict__ shiftp, const float* __restrict__ biasp,
    int s0, int s1)
{
    extern __shared__ short Buf[];
    unsigned* Buf32 = (unsigned*)Buf;

    const int bi   = blockIdx.x;
    const int b    = bi >> 7;
    const int i    = bi & 127;
    const int tid  = threadIdx.x;
    const int lane = tid & 63;
    const int w    = tid >> 6;

    const float shift = shiftp[0];
    const float bias  = biasp[0];

    const size_t obase_off = (size_t)b * (128 * 128 * 256) + (size_t)i * s0;
    const float* abase = atten + (size_t)bi * (128 * 128);
    const float* vbase = value + obase_off;

    const int rrow  = 16 * w + (lane & 15);     // this lane's output row
    const int kq8   = (lane >> 4) * 8;          // k-subchunk base (MFMA B layout)
    const int am    = lane & 15;
    const int dq    = 4 * (lane >> 4);
    const int k0    = 16 * w + 2 * (lane >> 3); // staging: even k-row (wave's 16 k)
    const int dl    = 4 * (lane & 7);           // staging: d-quad base within half
    const int col32 = k0 >> 1;                  // packed k-pair column

    // ---- A loads (nontemporal: stream-once, keep L3 for value/ws)
    floatx4 aA[8];
#pragma unroll
    for (int ks = 0; ks < 4; ++ks) {
        const float* ap = abase + rrow * 128 + ks * 32 + kq8;
        aA[2 * ks]     = __builtin_nontemporal_load((const floatx4*)(ap));
        aA[2 * ks + 1] = __builtin_nontemporal_load((const floatx4*)(ap + 4));
    }

    // ---- Softmax fully in place in aA (row-per-lane; 4 lanes share a row)
    short8 bfrag[4];
    {
        float mx = -1e30f;
#pragma unroll
        for (int j = 0; j < 8; ++j) {
            const int kb = (j >> 1) * 32 + kq8 + (j & 1) * 4;
            floatx4 t = aA[j];
#pragma unroll
            for (int e = 0; e < 4; ++e) {
                float d = (float)(kb + e - rrow);
                t[e] = t[e] - (shift * d * d + bias);
            }
            aA[j] = t;
            mx = fmaxf(mx, fmaxf(fmaxf(t[0], t[1]), fmaxf(t[2], t[3])));
        }
        mx = fmaxf(mx, __shfl_xor(mx, 16, 64));
        mx = fmaxf(mx, __shfl_xor(mx, 32, 64));
        float ssum = 0.0f;
#pragma unroll
        for (int j = 0; j < 8; ++j) {
            floatx4 t = aA[j];
#pragma unroll
            for (int e = 0; e < 4; ++e) t[e] = __expf(t[e] - mx);
            aA[j] = t;
            ssum += (t[0] + t[1]) + (t[2] + t[3]);
        }
        ssum += __shfl_xor(ssum, 16, 64);
        ssum += __shfl_xor(ssum, 32, 64);
        float r = 1.0f / ssum;
#pragma unroll
        for (int ks = 0; ks < 4; ++ks) {
            union { short8 s; unsigned u[4]; } uu;
            floatx4 lo = aA[2 * ks], hi = aA[2 * ks + 1];
            uu.u[0] = packbf(lo[0] * r, lo[1] * r);
            uu.u[1] = packbf(lo[2] * r, lo[3] * r);
            uu.u[2] = packbf(hi[0] * r, hi[1] * r);
            uu.u[3] = packbf(hi[2] * r, hi[3] * r);
            bfrag[ks] = uu.s;
        }
    }

    float*    orow = out + obase_off + (size_t)rrow * s1 + dq;
    _Float16* wrow = ws  + obase_off + (size_t)rrow * s1 + dq;

    // ---- Two d-halves: stage V^T [128 d][128 k], MFMA 8 d-tiles, retire acc
#pragma unroll
    for (int half = 0; half < 2; ++half) {
        // V loads: wave's 16 k-rows (8 even/odd pairs), this half's 128 d
        floatx4 va[4], vb[4];
        {
            const float* vp0 = vbase + (size_t)k0 * s1 + half * 128 + dl;
            const float* vp1 = vp0 + s1;
#pragma unroll
            for (int q = 0; q < 4; ++q) va[q] = *(const floatx4*)(vp0 + 32 * q);
#pragma unroll
            for (int q = 0; q < 4; ++q) vb[q] = *(const floatx4*)(vp1 + 32 * q);
        }
        // stage packed k-pairs: row = local d, col = k/2
#pragma unroll
        for (int q = 0; q < 4; ++q)
#pragma unroll
            for (int e = 0; e < 4; ++e)
                Buf32[(dl + 32 * q + e) * (LDK / 2) + col32] = packbf(va[q][e], vb[q][e]);

        __builtin_amdgcn_sched_barrier(0);
        asm volatile("s_waitcnt lgkmcnt(0)" ::: "memory");
        __builtin_amdgcn_s_barrier();

        // 2 groups x 4 d-tiles (16x16 each), k complete -> acc retires here
#pragma unroll
        for (int g = 0; g < 2; ++g) {
            const int cb = half * 128 + g * 64;   // output column base of group
            floatx4 acc[4];
            if (MODE == 2) {
#pragma unroll
                for (int t = 0; t < 4; ++t)
                    acc[t] = *(const floatx4*)(orow + cb + t * 16);
            } else if (MODE == 3) {
#pragma unroll
                for (int t = 0; t < 4; ++t) {
                    half4 h = *(const half4*)(wrow + cb + t * 16);
                    floatx4 f;
#pragma unroll
                    for (int e = 0; e < 4; ++e) f[e] = (float)h[e];
                    acc[t] = f;
                }
            } else {
#pragma unroll
                for (int t = 0; t < 4; ++t) acc[t] = (floatx4)0.0f;
            }
#pragma unroll
            for (int tt = 0; tt < 4; ++tt) {
                const short* base = &Buf[((g * 4 + tt) * 16 + am) * LDK + kq8];
#pragma unroll
                for (int ks = 0; ks < 4; ++ks) {
                    short8 af = *(const short8*)(base + ks * 32);
                    acc[tt] = __builtin_amdgcn_mfma_f32_16x16x32_bf16(af, bfrag[ks], acc[tt], 0, 0, 0);
                }
            }
#pragma unroll
            for (int t = 0; t < 4; ++t) {
                if (MODE == 1) {
                    half4 h;
#pragma unroll
                    for (int e = 0; e < 4; ++e) h[e] = (_Float16)acc[t][e];
                    *(half4*)(wrow + cb + t * 16) = h;
                } else if (MODE == 3) {
                    __builtin_nontemporal_store(acc[t], (floatx4*)(orow + cb + t * 16));
                } else {
                    *(floatx4*)(orow + cb + t * 16) = acc[t];
                }
            }
        }
        if (half == 0)
            __builtin_amdgcn_s_barrier();   // all LDS reads of half-0 retired before restage
    }
}

extern "C" void kernel_launch(void* const* d_in, const int* in_sizes, int n_in,
                              void* d_out, int out_size, void* d_ws, size_t ws_size,
                              hipStream_t stream) {
    const float* atten_x = (const float*)d_in[1];
    const float* atten_y = (const float*)d_in[2];
    const float* value   = (const float*)d_in[3];
    const float* shiftp  = (const float*)d_in[4];
    const float* biasp   = (const float*)d_in[5];
    float* out = (float*)d_out;
    _Float16* ws = (_Float16*)d_ws;

    static bool inited = false;
    if (!inited) {
        hipFuncSetAttribute((const void*)&gtrans<0>, hipFuncAttributeMaxDynamicSharedMemorySize, LDS_BYTES);
        hipFuncSetAttribute((const void*)&gtrans<1>, hipFuncAttributeMaxDynamicSharedMemorySize, LDS_BYTES);
        hipFuncSetAttribute((const void*)&gtrans<2>, hipFuncAttributeMaxDynamicSharedMemorySize, LDS_BYTES);
        hipFuncSetAttribute((const void*)&gtrans<3>, hipFuncAttributeMaxDynamicSharedMemorySize, LDS_BYTES);
        inited = true;
    }

    const bool use_ws = (ws != nullptr) && (ws_size >= (size_t)OUT_ELEMS * sizeof(_Float16));

    dim3 grid(1024), block(512);
    if (use_ws) {
        // Pass 1: ws(fp16) = einsum('brck,brkd->brcd', softmax(Ax+gx), value)
        gtrans<1><<<grid, block, LDS_BYTES, stream>>>(atten_x, value, out, ws, shiftp, biasp,
                                                      128 * 256, 256);
        // Pass 2: out = ws + einsum('bcrk,bkcd->brcd', softmax(Ay+gy), value)
        gtrans<3><<<grid, block, LDS_BYTES, stream>>>(atten_y, value, out, ws, shiftp, biasp,
                                                      256, 128 * 256);
    } else {
        gtrans<0><<<grid, block, LDS_BYTES, stream>>>(atten_x, value, out, ws, shiftp, biasp,
                                                      128 * 256, 256);
        gtrans<2><<<grid, block, LDS_BYTES, stream>>>(atten_y, value, out, ws, shiftp, biasp,
                                                      256, 128 * 256);
    }
}